// Round 6
// baseline (1350.052 us; speedup 1.0000x reference)
//
#include <hip/hip_runtime.h>
#include <math.h>

// NSF_CL coupling flow via bf16 MFMA. N=32768, dim=256 (half=128), hid=512, K=5.
// Round 5 (resubmit; r5 bench was an acquisition timeout): transpose-free phase 2
// (swapped-operand MFMA: A=w1 d-rows, B=h batch cols -> all 14 spline params land
// in one lane), bias folded as virtual k-tile, W/H/D p-group processing with
// cumsum-compressed state. 256 thr, BM=32, LDS 40KB -> 4 blocks/CU, <=128 VGPR.

#define NROWS 32768
#define DIMX  256
#define HALF  128
#define HID   512
#define BM    32

typedef __attribute__((ext_vector_type(8))) short short8;   // 8 bf16 = 4 VGPR
typedef __attribute__((ext_vector_type(4))) float f32x4;

__device__ __forceinline__ unsigned short f2bf(float x) {   // RNE f32->bf16 bits
    unsigned int u = __float_as_uint(x);
    u += 0x7fffu + ((u >> 16) & 1u);
    return (unsigned short)(u >> 16);
}

__device__ __forceinline__ float frcp(float x) { return __builtin_amdgcn_rcpf(x); }

__device__ __forceinline__ float spf(float x) {             // fast softplus
    return fmaxf(x, 0.f) + __logf(1.f + __expf(-fabsf(x)));
}

// cs[p] = cumsum_{0..p} of (1e-3 + 0.995*softmax(6*softmax(P))), p=0..3 (cs[4]==1)
__device__ __forceinline__ void dsm5_cs(const float* P, float* cs) {
    float e[5];
    float m = fmaxf(fmaxf(fmaxf(P[0], P[1]), fmaxf(P[2], P[3])), P[4]);
    float s = 0.f;
    #pragma unroll
    for (int p = 0; p < 5; ++p) { e[p] = __expf(P[p] - m); s += e[p]; }
    float r = 6.f * frcp(s);
    float s2 = 0.f;
    #pragma unroll
    for (int p = 0; p < 5; ++p) { e[p] = __expf(e[p] * r); s2 += e[p]; }
    float r2 = 0.995f * frcp(s2);
    float run = 0.f;
    #pragma unroll
    for (int p = 0; p < 4; ++p) { run += e[p]; cs[p] = (float)(p + 1) * 1.0e-3f + r2 * run; }
}

// csw/csh: knot cumsums (4 each); dvi: interior derivs (4). Same numerics as r3.
__device__ __forceinline__ void rqs_cs(const float* csw, const float* csh, const float* dvi,
                                       float xa, float& yo, float& ldo) {
    float xc = fminf(fmaxf(xa, -3.f), 3.f);
    float in_cw = -3.f, in_ch = -3.f;
    float in_w = 6.f * csw[0], in_h = 6.f * csh[0];
    float dk = 1.f, dk1 = dvi[0];
    #pragma unroll
    for (int p = 1; p < 5; ++p) {
        float cwp = 6.f * csw[p - 1] - 3.f;
        float chp = 6.f * csh[p - 1] - 3.f;
        float cwp1 = (p == 4) ? 3.f : (6.f * csw[p] - 3.f);
        float chp1 = (p == 4) ? 3.f : (6.f * csh[p] - 3.f);
        bool take = (xc >= cwp);
        in_cw = take ? cwp : in_cw;
        in_w  = take ? (cwp1 - cwp) : in_w;
        in_ch = take ? chp : in_ch;
        in_h  = take ? (chp1 - chp) : in_h;
        dk    = take ? dvi[p - 1] : dk;
        dk1   = take ? ((p == 4) ? 1.f : dvi[p]) : dk1;
    }
    float rw = frcp(in_w);
    float th = (xc - in_cw) * rw;
    float om = 1.f - th;
    float t1m = th * om;
    float delta = in_h * rw;
    float num = in_h * (delta * th * th + dk * t1m);
    float den = delta + (dk + dk1 - 2.f * delta) * t1m;
    float y = in_ch + num * frcp(den);
    float dnum = delta * delta * (dk1 * th * th + 2.f * delta * t1m + dk * om * om);
    float ld = __logf(dnum) - 2.f * __logf(den);
    bool inside = (xa >= -3.f) && (xa <= 3.f);
    yo  = inside ? y : xa;
    ldo = inside ? ld : 0.f;
}

// ---------- prep ----------
// w1f[stage][frag=(dblk*17+c2)*14+p][lane 64] = ushort8:
//   c2<16 : e -> w1[k=32*c2+8*(l>>4)+e][(dblk*16+(l&15))*14+p]
//   c2==16: e==0 && (l>>4)==0 -> b1[(dblk*16+(l&15))*14+p], else 0   (bias k-tile)
// w0f[stage][ct 32][c 4][lane 64] = ushort8: e -> w0[k=32*c+8*(l>>4)+e][ct*16+(l&15)]
#define W1FRAGS 1904                 // 8*17*14
#define W1ELEMS (W1FRAGS * 64)       // per-stage short8 count = 121856
__global__ void prep(const float* __restrict__ w1a, const float* __restrict__ w1b,
                     const float* __restrict__ w0a, const float* __restrict__ w0b,
                     const float* __restrict__ b1a, const float* __restrict__ b1b,
                     short* __restrict__ w1f, short* __restrict__ w0f) {
    int idx = blockIdx.x * 256 + threadIdx.x;
    if (idx < 2 * W1ELEMS) {
        int s = idx / W1ELEMS;
        int rem = idx - s * W1ELEMS;
        int frag = rem >> 6, l = rem & 63;
        int p = frag % 14;
        int t = frag / 14;
        int c2 = t % 17;
        int dblk = t / 17;
        const float* w1s = s ? w1b : w1a;
        const float* b1s = s ? b1b : b1a;
        int col = (dblk * 16 + (l & 15)) * 14 + p;
        int g = l >> 4;
        short8 o;
        #pragma unroll
        for (int e = 0; e < 8; ++e) {
            float v;
            if (c2 < 16) {
                int k = 32 * c2 + 8 * g + e;
                v = w1s[(size_t)k * 1792 + col];
            } else {
                v = (g == 0 && e == 0) ? b1s[col] : 0.f;
            }
            o[e] = (short)f2bf(v);
        }
        *reinterpret_cast<short8*>(w1f + ((size_t)s * W1ELEMS + rem) * 8) = o;
    } else if (idx < 2 * W1ELEMS + 16384) {
        int r = idx - 2 * W1ELEMS;
        int s = r >> 13, rem = r & 8191;
        int l = rem & 63;
        const float* src = s ? w0b : w0a;
        int p = l & 15, g = l >> 4;
        int ct = rem >> 8, c = (rem >> 6) & 3;
        short8 o;
        #pragma unroll
        for (int e = 0; e < 8; ++e) {
            int k = 32 * c + 8 * g + e;
            o[e] = (short)f2bf(src[k * 512 + ct * 16 + p]);
        }
        *reinterpret_cast<short8*>(w0f + s * 65536 + rem * 8) = o;
    }
}

// ---------- fused stage kernel: 4 waves, 32 rows/block ----------
template <int STAGE>
__global__ __launch_bounds__(256, 4)
void nsf_stage(const float* __restrict__ xin, float* __restrict__ zout,
               float* __restrict__ ld_out,
               const short* __restrict__ w0f, const float* __restrict__ b0,
               const short* __restrict__ w1f) {
    __shared__ __align__(16) short hA2[16384];   // 32 KB: [rt 2][c2 16][lane 64][e 8] bf16
    __shared__ __align__(16) float aux[2048];    // 8 KB: A1 alias (phase 0/1), ld reduce (end)
    short* A1 = reinterpret_cast<short*>(aux);   // 8 frags x 64 lanes x 8 bf16 = 8 KB

    const int tid = threadIdx.x;
    const int lane = tid & 63;
    const int w = tid >> 6;
    const int n0 = blockIdx.x * BM;

    const float* cond = STAGE ? zout : xin;
    const int coff = STAGE ? HALF : 0;
    const int aoff = STAGE ? 0 : HALF;
    const int yoff = STAGE ? 0 : HALF;

    // ---- phase 0: cond tile [32][128] -> bf16 A1 fragments
    #pragma unroll
    for (int t = 0; t < 2; ++t) {
        int idx = t * 256 + tid;             // 8 frags x 64 lanes
        int fr = idx >> 6, l = idx & 63;
        int rt = fr >> 2, c = fr & 3;
        int row = rt * 16 + (l & 15);
        int kb = 32 * c + 8 * (l >> 4);
        const float* sp = cond + (size_t)(n0 + row) * DIMX + coff + kb;
        short8 o;
        #pragma unroll
        for (int e = 0; e < 8; ++e) o[e] = (short)f2bf(sp[e]);
        *reinterpret_cast<short8*>(A1 + idx * 8) = o;
    }
    __syncthreads();

    // ---- phase 1: h = tanh(cond @ w0 + b0) -> bf16 frag order in hA2
    for (int rt = 0; rt < 2; ++rt) {
        short8 a1[4];
        #pragma unroll
        for (int c = 0; c < 4; ++c)
            a1[c] = *reinterpret_cast<const short8*>(A1 + ((rt * 4 + c) * 64 + lane) * 8);
        #pragma unroll
        for (int j = 0; j < 8; ++j) {
            int ct = w * 8 + j;
            f32x4 acc = {0.f, 0.f, 0.f, 0.f};
            #pragma unroll
            for (int c = 0; c < 4; ++c) {
                short8 b = *reinterpret_cast<const short8*>(w0f + ((ct * 4 + c) * 64 + lane) * 8);
                acc = __builtin_amdgcn_mfma_f32_16x16x32_bf16(a1[c], b, acc, 0, 0, 0);
            }
            float bv = b0[ct * 16 + (lane & 15)];
            int q = (2 * ct + ((lane & 15) >> 3)) & 3;
            int c2 = ct >> 1;
            #pragma unroll
            for (int r = 0; r < 4; ++r) {
                float av = acc[r] + bv;
                float e2 = __expf(2.f * av);
                float hvf = 1.f - 2.f * frcp(e2 + 1.f);
                int i = (lane >> 4) * 4 + r;
                hA2[((rt * 16 + c2) * 64 + (i + 16 * q)) * 8 + (lane & 7)] = (short)f2bf(hvf);
            }
        }
    }
    __syncthreads();

    // ---- phase 2: per d-block (16 d), swapped-operand GEMM2 in 3 p-groups + spline
    float ldacc[2] = {0.f, 0.f};
    short8 vone = {0, 0, 0, 0, 0, 0, 0, 0};     // virtual bias k-tile B-frag: h'=1 at k-off 0
    if (lane < 16) vone[0] = (short)0x3F80;      // bf16 1.0

    for (int db = 0; db < 2; ++db) {
        const int dblk = w * 2 + db;
        const short* wbase = w1f + (size_t)dblk * 17 * 14 * 512;
        float csW[2][4][4], csH[2][4][4], dvi[2][4][4];   // [q][idx][r]

        // --- group W: p = 0..4
        {
            f32x4 acc[2][5];
            #pragma unroll
            for (int q = 0; q < 2; ++q)
                #pragma unroll
                for (int p = 0; p < 5; ++p) acc[q][p] = (f32x4){0.f, 0.f, 0.f, 0.f};
            for (int c2 = 0; c2 < 17; ++c2) {
                short8 hb0 = (c2 < 16) ? *reinterpret_cast<const short8*>(hA2 + (c2 * 64 + lane) * 8) : vone;
                short8 hb1 = (c2 < 16) ? *reinterpret_cast<const short8*>(hA2 + ((16 + c2) * 64 + lane) * 8) : vone;
                const short* fb = wbase + (size_t)c2 * 14 * 512 + lane * 8;
                #pragma unroll
                for (int p = 0; p < 5; ++p) {
                    short8 af = *reinterpret_cast<const short8*>(fb + p * 512);
                    acc[0][p] = __builtin_amdgcn_mfma_f32_16x16x32_bf16(af, hb0, acc[0][p], 0, 0, 0);
                    acc[1][p] = __builtin_amdgcn_mfma_f32_16x16x32_bf16(af, hb1, acc[1][p], 0, 0, 0);
                }
            }
            #pragma unroll
            for (int q = 0; q < 2; ++q)
                #pragma unroll
                for (int r = 0; r < 4; ++r) {
                    float P[5] = {acc[q][0][r], acc[q][1][r], acc[q][2][r], acc[q][3][r], acc[q][4][r]};
                    float cs[4];
                    dsm5_cs(P, cs);
                    #pragma unroll
                    for (int i = 0; i < 4; ++i) csW[q][i][r] = cs[i];
                }
        }
        // --- group H: p = 5..9
        {
            f32x4 acc[2][5];
            #pragma unroll
            for (int q = 0; q < 2; ++q)
                #pragma unroll
                for (int p = 0; p < 5; ++p) acc[q][p] = (f32x4){0.f, 0.f, 0.f, 0.f};
            for (int c2 = 0; c2 < 17; ++c2) {
                short8 hb0 = (c2 < 16) ? *reinterpret_cast<const short8*>(hA2 + (c2 * 64 + lane) * 8) : vone;
                short8 hb1 = (c2 < 16) ? *reinterpret_cast<const short8*>(hA2 + ((16 + c2) * 64 + lane) * 8) : vone;
                const short* fb = wbase + (size_t)c2 * 14 * 512 + lane * 8;
                #pragma unroll
                for (int p = 0; p < 5; ++p) {
                    short8 af = *reinterpret_cast<const short8*>(fb + (5 + p) * 512);
                    acc[0][p] = __builtin_amdgcn_mfma_f32_16x16x32_bf16(af, hb0, acc[0][p], 0, 0, 0);
                    acc[1][p] = __builtin_amdgcn_mfma_f32_16x16x32_bf16(af, hb1, acc[1][p], 0, 0, 0);
                }
            }
            #pragma unroll
            for (int q = 0; q < 2; ++q)
                #pragma unroll
                for (int r = 0; r < 4; ++r) {
                    float P[5] = {acc[q][0][r], acc[q][1][r], acc[q][2][r], acc[q][3][r], acc[q][4][r]};
                    float cs[4];
                    dsm5_cs(P, cs);
                    #pragma unroll
                    for (int i = 0; i < 4; ++i) csH[q][i][r] = cs[i];
                }
        }
        // --- group D: p = 10..13
        {
            f32x4 acc[2][4];
            #pragma unroll
            for (int q = 0; q < 2; ++q)
                #pragma unroll
                for (int p = 0; p < 4; ++p) acc[q][p] = (f32x4){0.f, 0.f, 0.f, 0.f};
            for (int c2 = 0; c2 < 17; ++c2) {
                short8 hb0 = (c2 < 16) ? *reinterpret_cast<const short8*>(hA2 + (c2 * 64 + lane) * 8) : vone;
                short8 hb1 = (c2 < 16) ? *reinterpret_cast<const short8*>(hA2 + ((16 + c2) * 64 + lane) * 8) : vone;
                const short* fb = wbase + (size_t)c2 * 14 * 512 + lane * 8;
                #pragma unroll
                for (int p = 0; p < 4; ++p) {
                    short8 af = *reinterpret_cast<const short8*>(fb + (10 + p) * 512);
                    acc[0][p] = __builtin_amdgcn_mfma_f32_16x16x32_bf16(af, hb0, acc[0][p], 0, 0, 0);
                    acc[1][p] = __builtin_amdgcn_mfma_f32_16x16x32_bf16(af, hb1, acc[1][p], 0, 0, 0);
                }
            }
            #pragma unroll
            for (int q = 0; q < 2; ++q)
                #pragma unroll
                for (int r = 0; r < 4; ++r)
                    #pragma unroll
                    for (int p = 0; p < 4; ++p)
                        dvi[q][p][r] = 1.0e-3f + spf(spf(acc[q][p][r]));
        }
        // --- spline: lane -> (row = lane&15 of tile q, d = dblk*16 + (lane>>4)*4 + r)
        #pragma unroll
        for (int q = 0; q < 2; ++q) {
            #pragma unroll
            for (int r = 0; r < 4; ++r) {
                float cw_[4] = {csW[q][0][r], csW[q][1][r], csW[q][2][r], csW[q][3][r]};
                float ch_[4] = {csH[q][0][r], csH[q][1][r], csH[q][2][r], csH[q][3][r]};
                float dv_[4] = {dvi[q][0][r], dvi[q][1][r], dvi[q][2][r], dvi[q][3][r]};
                int n = n0 + q * 16 + (lane & 15);
                int d = dblk * 16 + (lane >> 4) * 4 + r;
                float xa = xin[(size_t)n * DIMX + aoff + d];
                float y, ldv;
                rqs_cs(cw_, ch_, dv_, xa, y, ldv);
                zout[(size_t)n * DIMX + yoff + d] = y;
                ldacc[q] += ldv;
            }
        }
    }

    // ---- log-det reduce: within wave (d-groups), then across waves via aux
    float s0 = ldacc[0], s1 = ldacc[1];
    s0 += __shfl_xor(s0, 16, 64); s0 += __shfl_xor(s0, 32, 64);
    s1 += __shfl_xor(s1, 16, 64); s1 += __shfl_xor(s1, 32, 64);
    __syncthreads();                             // A1 region long done; order before reuse
    if (lane < 16) {
        aux[w * 32 + lane] = s0;
        aux[w * 32 + 16 + lane] = s1;
    }
    __syncthreads();
    if (tid < BM) {
        float s = aux[tid] + aux[32 + tid] + aux[64 + tid] + aux[96 + tid];
        if (STAGE == 0) ld_out[n0 + tid] = s;
        else            ld_out[n0 + tid] += s;
    }
}

// ---------- launch ----------
extern "C" void kernel_launch(void* const* d_in, const int* in_sizes, int n_in,
                              void* d_out, int out_size, void* d_ws, size_t ws_size,
                              hipStream_t stream) {
    const float* x     = (const float*)d_in[0];
    const float* f0_w0 = (const float*)d_in[1];
    const float* f0_b0 = (const float*)d_in[2];
    const float* f0_w1 = (const float*)d_in[3];
    const float* f0_b1 = (const float*)d_in[4];
    const float* f1_w0 = (const float*)d_in[5];
    const float* f1_b0 = (const float*)d_in[6];
    const float* f1_w1 = (const float*)d_in[7];
    const float* f1_b1 = (const float*)d_in[8];

    float* zout = (float*)d_out;
    float* ld   = zout + (size_t)NROWS * DIMX;

    short* w1f = (short*)d_ws;                                   // 2 x 1.86 MB
    short* w0f = (short*)((char*)d_ws + (size_t)2 * W1ELEMS * 16); // 2 x 128 KB

    prep<<<1016, 256, 0, stream>>>(f0_w1, f1_w1, f0_w0, f1_w0, f0_b1, f1_b1, w1f, w0f);
    nsf_stage<0><<<NROWS / BM, 256, 0, stream>>>(x, zout, ld, w0f, f0_b0, w1f);
    nsf_stage<1><<<NROWS / BM, 256, 0, stream>>>(x, zout, ld, w0f + 65536, f1_b0,
                                                 w1f + (size_t)W1ELEMS * 8);
}

// Round 7
// 604.886 us; speedup vs baseline: 2.2319x; 2.2319x over previous
//
#include <hip/hip_runtime.h>
#include <math.h>

// NSF_CL coupling flow via bf16 MFMA. N=32768, dim=256 (half=128), hid=512, K=5.
// Round 7: r5 structure (transpose-free swapped-operand GEMM2, bias as virtual
// k-tile) with SLIM persistent state: reduce each p-group to final spline scalars
// immediately (idx decided right after W-group since xa is pre-loaded).
// Persistent per-thread state 43 f32 (was 96) -> no spill at launch_bounds(256,3).

#define NROWS 32768
#define DIMX  256
#define HALF  128
#define HID   512
#define BM    32

typedef __attribute__((ext_vector_type(8))) short short8;   // 8 bf16 = 4 VGPR
typedef __attribute__((ext_vector_type(4))) float f32x4;

__device__ __forceinline__ unsigned short f2bf(float x) {   // RNE f32->bf16 bits
    unsigned int u = __float_as_uint(x);
    u += 0x7fffu + ((u >> 16) & 1u);
    return (unsigned short)(u >> 16);
}

__device__ __forceinline__ float frcp(float x) { return __builtin_amdgcn_rcpf(x); }

__device__ __forceinline__ float spf(float x) {             // fast softplus
    return fmaxf(x, 0.f) + __logf(1.f + __expf(-fabsf(x)));
}

// cs[p] = cumsum_{0..p} of (1e-3 + 0.995*softmax(6*softmax(P))), p=0..3 (cs[4]==1)
__device__ __forceinline__ void dsm5_cs(const float* P, float* cs) {
    float e[5];
    float m = fmaxf(fmaxf(fmaxf(P[0], P[1]), fmaxf(P[2], P[3])), P[4]);
    float s = 0.f;
    #pragma unroll
    for (int p = 0; p < 5; ++p) { e[p] = __expf(P[p] - m); s += e[p]; }
    float r = 6.f * frcp(s);
    float s2 = 0.f;
    #pragma unroll
    for (int p = 0; p < 5; ++p) { e[p] = __expf(e[p] * r); s2 += e[p]; }
    float r2 = 0.995f * frcp(s2);
    float run = 0.f;
    #pragma unroll
    for (int p = 0; p < 4; ++p) { run += e[p]; cs[p] = (float)(p + 1) * 1.0e-3f + r2 * run; }
}

// ---------- prep ----------
// w1f[stage][frag=(dblk*17+c2)*14+p][lane 64] = ushort8:
//   c2<16 : e -> w1[k=32*c2+8*(l>>4)+e][(dblk*16+(l&15))*14+p]
//   c2==16: e==0 && (l>>4)==0 -> b1[(dblk*16+(l&15))*14+p], else 0   (bias k-tile)
// w0f[stage][ct 32][c 4][lane 64] = ushort8: e -> w0[k=32*c+8*(l>>4)+e][ct*16+(l&15)]
#define W1FRAGS 1904                 // 8*17*14
#define W1ELEMS (W1FRAGS * 64)       // per-stage short8 count = 121856
__global__ void prep(const float* __restrict__ w1a, const float* __restrict__ w1b,
                     const float* __restrict__ w0a, const float* __restrict__ w0b,
                     const float* __restrict__ b1a, const float* __restrict__ b1b,
                     short* __restrict__ w1f, short* __restrict__ w0f) {
    int idx = blockIdx.x * 256 + threadIdx.x;
    if (idx < 2 * W1ELEMS) {
        int s = idx / W1ELEMS;
        int rem = idx - s * W1ELEMS;
        int frag = rem >> 6, l = rem & 63;
        int p = frag % 14;
        int t = frag / 14;
        int c2 = t % 17;
        int dblk = t / 17;
        const float* w1s = s ? w1b : w1a;
        const float* b1s = s ? b1b : b1a;
        int col = (dblk * 16 + (l & 15)) * 14 + p;
        int g = l >> 4;
        short8 o;
        #pragma unroll
        for (int e = 0; e < 8; ++e) {
            float v;
            if (c2 < 16) {
                int k = 32 * c2 + 8 * g + e;
                v = w1s[(size_t)k * 1792 + col];
            } else {
                v = (g == 0 && e == 0) ? b1s[col] : 0.f;
            }
            o[e] = (short)f2bf(v);
        }
        *reinterpret_cast<short8*>(w1f + ((size_t)s * W1ELEMS + rem) * 8) = o;
    } else if (idx < 2 * W1ELEMS + 16384) {
        int r = idx - 2 * W1ELEMS;
        int s = r >> 13, rem = r & 8191;
        int l = rem & 63;
        const float* src = s ? w0b : w0a;
        int p = l & 15, g = l >> 4;
        int ct = rem >> 8, c = (rem >> 6) & 3;
        short8 o;
        #pragma unroll
        for (int e = 0; e < 8; ++e) {
            int k = 32 * c + 8 * g + e;
            o[e] = (short)f2bf(src[k * 512 + ct * 16 + p]);
        }
        *reinterpret_cast<short8*>(w0f + s * 65536 + rem * 8) = o;
    }
}

// ---------- fused stage kernel: 4 waves, 32 rows/block ----------
template <int STAGE>
__global__ __launch_bounds__(256, 3)
void nsf_stage(const float* __restrict__ xin, float* __restrict__ zout,
               float* __restrict__ ld_out,
               const short* __restrict__ w0f, const float* __restrict__ b0,
               const short* __restrict__ w1f) {
    __shared__ __align__(16) short hA2[16384];   // 32 KB: [rt 2][c2 16][lane 64][e 8] bf16
    __shared__ __align__(16) float aux[2048];    // 8 KB: A1 alias (phase 0/1), ld reduce (end)
    short* A1 = reinterpret_cast<short*>(aux);   // 8 frags x 64 lanes x 8 bf16 = 8 KB

    const int tid = threadIdx.x;
    const int lane = tid & 63;
    const int w = tid >> 6;
    const int n0 = blockIdx.x * BM;

    const float* cond = STAGE ? zout : xin;
    const int coff = STAGE ? HALF : 0;
    const int aoff = STAGE ? 0 : HALF;
    const int yoff = STAGE ? 0 : HALF;

    // ---- phase 0: cond tile [32][128] -> bf16 A1 fragments
    #pragma unroll
    for (int t = 0; t < 2; ++t) {
        int idx = t * 256 + tid;             // 8 frags x 64 lanes
        int fr = idx >> 6, l = idx & 63;
        int rt = fr >> 2, c = fr & 3;
        int row = rt * 16 + (l & 15);
        int kb = 32 * c + 8 * (l >> 4);
        const float* sp = cond + (size_t)(n0 + row) * DIMX + coff + kb;
        short8 o;
        #pragma unroll
        for (int e = 0; e < 8; ++e) o[e] = (short)f2bf(sp[e]);
        *reinterpret_cast<short8*>(A1 + idx * 8) = o;
    }
    __syncthreads();

    // ---- phase 1: h = tanh(cond @ w0 + b0) -> bf16 frag order in hA2
    for (int rt = 0; rt < 2; ++rt) {
        short8 a1[4];
        #pragma unroll
        for (int c = 0; c < 4; ++c)
            a1[c] = *reinterpret_cast<const short8*>(A1 + ((rt * 4 + c) * 64 + lane) * 8);
        #pragma unroll
        for (int j = 0; j < 8; ++j) {
            int ct = w * 8 + j;
            f32x4 acc = {0.f, 0.f, 0.f, 0.f};
            #pragma unroll
            for (int c = 0; c < 4; ++c) {
                short8 b = *reinterpret_cast<const short8*>(w0f + ((ct * 4 + c) * 64 + lane) * 8);
                acc = __builtin_amdgcn_mfma_f32_16x16x32_bf16(a1[c], b, acc, 0, 0, 0);
            }
            float bv = b0[ct * 16 + (lane & 15)];
            int q = (2 * ct + ((lane & 15) >> 3)) & 3;
            int c2 = ct >> 1;
            #pragma unroll
            for (int r = 0; r < 4; ++r) {
                float av = acc[r] + bv;
                float e2 = __expf(2.f * av);
                float hvf = 1.f - 2.f * frcp(e2 + 1.f);
                int i = (lane >> 4) * 4 + r;
                hA2[((rt * 16 + c2) * 64 + (i + 16 * q)) * 8 + (lane & 7)] = (short)f2bf(hvf);
            }
        }
    }
    __syncthreads();

    // ---- phase 2: per d-block (16 d), swapped-operand GEMM2 in 3 p-groups.
    // Persistent per tuple (q in 2, r in 4): xa, th, rw (after W), in_ch, in_h
    // (after H); 3-bit bucket idx packed in one uint. D-group finishes in place.
    float ldacc[2] = {0.f, 0.f};
    short8 vone = {0, 0, 0, 0, 0, 0, 0, 0};     // virtual bias k-tile B-frag
    if (lane < 16) vone[0] = (short)0x3F80;      // bf16 1.0

    for (int db = 0; db < 2; ++db) {
        const int dblk = w * 2 + db;
        const short* wbase = w1f + (size_t)dblk * 17 * 14 * 512;
        float xa[2][4], th[2][4], rw[2][4], inch[2][4], inh[2][4];
        unsigned idxp = 0;

        #pragma unroll
        for (int q = 0; q < 2; ++q)
            #pragma unroll
            for (int r = 0; r < 4; ++r) {
                int n = n0 + q * 16 + (lane & 15);
                int d = dblk * 16 + (lane >> 4) * 4 + r;
                xa[q][r] = xin[(size_t)n * DIMX + aoff + d];
            }

        // --- group W: p = 0..4 -> th, rw, idx
        {
            f32x4 acc[2][5];
            #pragma unroll
            for (int q = 0; q < 2; ++q)
                #pragma unroll
                for (int p = 0; p < 5; ++p) acc[q][p] = (f32x4){0.f, 0.f, 0.f, 0.f};
            for (int c2 = 0; c2 < 17; ++c2) {
                short8 hb0 = (c2 < 16) ? *reinterpret_cast<const short8*>(hA2 + (c2 * 64 + lane) * 8) : vone;
                short8 hb1 = (c2 < 16) ? *reinterpret_cast<const short8*>(hA2 + ((16 + c2) * 64 + lane) * 8) : vone;
                const short* fb = wbase + (size_t)c2 * 14 * 512 + lane * 8;
                #pragma unroll
                for (int p = 0; p < 5; ++p) {
                    short8 af = *reinterpret_cast<const short8*>(fb + p * 512);
                    acc[0][p] = __builtin_amdgcn_mfma_f32_16x16x32_bf16(af, hb0, acc[0][p], 0, 0, 0);
                    acc[1][p] = __builtin_amdgcn_mfma_f32_16x16x32_bf16(af, hb1, acc[1][p], 0, 0, 0);
                }
            }
            #pragma unroll
            for (int q = 0; q < 2; ++q)
                #pragma unroll
                for (int r = 0; r < 4; ++r) {
                    float P[5] = {acc[q][0][r], acc[q][1][r], acc[q][2][r], acc[q][3][r], acc[q][4][r]};
                    float cs[4];
                    dsm5_cs(P, cs);
                    float xc = fminf(fmaxf(xa[q][r], -3.f), 3.f);
                    float in_cw = -3.f, in_w = 6.f * cs[0];
                    int idx = 0;
                    #pragma unroll
                    for (int p = 1; p < 5; ++p) {
                        float cwp = 6.f * cs[p - 1] - 3.f;
                        float cwp1 = (p == 4) ? 3.f : (6.f * cs[p] - 3.f);
                        bool take = (xc >= cwp);
                        in_cw = take ? cwp : in_cw;
                        in_w  = take ? (cwp1 - cwp) : in_w;
                        idx   = take ? p : idx;
                    }
                    float rwv = frcp(in_w);
                    rw[q][r] = rwv;
                    th[q][r] = (xc - in_cw) * rwv;
                    idxp |= (unsigned)idx << (3 * (q * 4 + r));
                }
        }
        // --- group H: p = 5..9 -> in_ch, in_h
        {
            f32x4 acc[2][5];
            #pragma unroll
            for (int q = 0; q < 2; ++q)
                #pragma unroll
                for (int p = 0; p < 5; ++p) acc[q][p] = (f32x4){0.f, 0.f, 0.f, 0.f};
            for (int c2 = 0; c2 < 17; ++c2) {
                short8 hb0 = (c2 < 16) ? *reinterpret_cast<const short8*>(hA2 + (c2 * 64 + lane) * 8) : vone;
                short8 hb1 = (c2 < 16) ? *reinterpret_cast<const short8*>(hA2 + ((16 + c2) * 64 + lane) * 8) : vone;
                const short* fb = wbase + (size_t)c2 * 14 * 512 + lane * 8;
                #pragma unroll
                for (int p = 0; p < 5; ++p) {
                    short8 af = *reinterpret_cast<const short8*>(fb + (5 + p) * 512);
                    acc[0][p] = __builtin_amdgcn_mfma_f32_16x16x32_bf16(af, hb0, acc[0][p], 0, 0, 0);
                    acc[1][p] = __builtin_amdgcn_mfma_f32_16x16x32_bf16(af, hb1, acc[1][p], 0, 0, 0);
                }
            }
            #pragma unroll
            for (int q = 0; q < 2; ++q)
                #pragma unroll
                for (int r = 0; r < 4; ++r) {
                    float P[5] = {acc[q][0][r], acc[q][1][r], acc[q][2][r], acc[q][3][r], acc[q][4][r]};
                    float cs[4];
                    dsm5_cs(P, cs);
                    int idx = (int)((idxp >> (3 * (q * 4 + r))) & 7u);
                    float lo = -3.f, hi = 6.f * cs[0] - 3.f;
                    #pragma unroll
                    for (int p = 1; p < 5; ++p) {
                        float clo = 6.f * cs[p - 1] - 3.f;
                        float chi = (p == 4) ? 3.f : (6.f * cs[p] - 3.f);
                        bool t = (idx >= p);
                        lo = t ? clo : lo;
                        hi = t ? chi : hi;
                    }
                    inch[q][r] = lo;
                    inh[q][r]  = hi - lo;
                }
        }
        // --- group D: p = 10..13 -> dk, dk1; finish spline
        {
            f32x4 acc[2][4];
            #pragma unroll
            for (int q = 0; q < 2; ++q)
                #pragma unroll
                for (int p = 0; p < 4; ++p) acc[q][p] = (f32x4){0.f, 0.f, 0.f, 0.f};
            for (int c2 = 0; c2 < 17; ++c2) {
                short8 hb0 = (c2 < 16) ? *reinterpret_cast<const short8*>(hA2 + (c2 * 64 + lane) * 8) : vone;
                short8 hb1 = (c2 < 16) ? *reinterpret_cast<const short8*>(hA2 + ((16 + c2) * 64 + lane) * 8) : vone;
                const short* fb = wbase + (size_t)c2 * 14 * 512 + lane * 8;
                #pragma unroll
                for (int p = 0; p < 4; ++p) {
                    short8 af = *reinterpret_cast<const short8*>(fb + (10 + p) * 512);
                    acc[0][p] = __builtin_amdgcn_mfma_f32_16x16x32_bf16(af, hb0, acc[0][p], 0, 0, 0);
                    acc[1][p] = __builtin_amdgcn_mfma_f32_16x16x32_bf16(af, hb1, acc[1][p], 0, 0, 0);
                }
            }
            #pragma unroll
            for (int q = 0; q < 2; ++q)
                #pragma unroll
                for (int r = 0; r < 4; ++r) {
                    float dvi[4];
                    #pragma unroll
                    for (int p = 0; p < 4; ++p) dvi[p] = 1.0e-3f + spf(spf(acc[q][p][r]));
                    int idx = (int)((idxp >> (3 * (q * 4 + r))) & 7u);
                    float dk = 1.f, dk1 = dvi[0];
                    #pragma unroll
                    for (int p = 1; p < 5; ++p) {
                        bool t = (idx >= p);
                        dk = t ? dvi[p - 1] : dk;
                    }
                    #pragma unroll
                    for (int p = 1; p < 4; ++p) {
                        bool t = (idx >= p);
                        dk1 = t ? dvi[p] : dk1;
                    }
                    dk1 = (idx >= 4) ? 1.f : dk1;

                    float xav = xa[q][r], thv = th[q][r], rwv = rw[q][r];
                    float hin = inh[q][r];
                    float om = 1.f - thv;
                    float t1m = thv * om;
                    float delta = hin * rwv;
                    float num = hin * (delta * thv * thv + dk * t1m);
                    float den = delta + (dk + dk1 - 2.f * delta) * t1m;
                    float y = inch[q][r] + num * frcp(den);
                    float dnum = delta * delta * (dk1 * thv * thv + 2.f * delta * t1m + dk * om * om);
                    float ld = __logf(dnum) - 2.f * __logf(den);
                    bool inside = (xav >= -3.f) && (xav <= 3.f);
                    y  = inside ? y : xav;
                    ld = inside ? ld : 0.f;

                    int n = n0 + q * 16 + (lane & 15);
                    int d = dblk * 16 + (lane >> 4) * 4 + r;
                    zout[(size_t)n * DIMX + yoff + d] = y;
                    ldacc[q] += ld;
                }
        }
    }

    // ---- log-det reduce: within wave (d-groups), then across waves via aux
    float s0 = ldacc[0], s1 = ldacc[1];
    s0 += __shfl_xor(s0, 16, 64); s0 += __shfl_xor(s0, 32, 64);
    s1 += __shfl_xor(s1, 16, 64); s1 += __shfl_xor(s1, 32, 64);
    __syncthreads();                             // A1 region long done; order before reuse
    if (lane < 16) {
        aux[w * 32 + lane] = s0;
        aux[w * 32 + 16 + lane] = s1;
    }
    __syncthreads();
    if (tid < BM) {
        float s = aux[tid] + aux[32 + tid] + aux[64 + tid] + aux[96 + tid];
        if (STAGE == 0) ld_out[n0 + tid] = s;
        else            ld_out[n0 + tid] += s;
    }
}

// ---------- launch ----------
extern "C" void kernel_launch(void* const* d_in, const int* in_sizes, int n_in,
                              void* d_out, int out_size, void* d_ws, size_t ws_size,
                              hipStream_t stream) {
    const float* x     = (const float*)d_in[0];
    const float* f0_w0 = (const float*)d_in[1];
    const float* f0_b0 = (const float*)d_in[2];
    const float* f0_w1 = (const float*)d_in[3];
    const float* f0_b1 = (const float*)d_in[4];
    const float* f1_w0 = (const float*)d_in[5];
    const float* f1_b0 = (const float*)d_in[6];
    const float* f1_w1 = (const float*)d_in[7];
    const float* f1_b1 = (const float*)d_in[8];

    float* zout = (float*)d_out;
    float* ld   = zout + (size_t)NROWS * DIMX;

    short* w1f = (short*)d_ws;                                   // 2 x 1.86 MB
    short* w0f = (short*)((char*)d_ws + (size_t)2 * W1ELEMS * 16); // 2 x 128 KB

    prep<<<1016, 256, 0, stream>>>(f0_w1, f1_w1, f0_w0, f1_w0, f0_b1, f1_b1, w1f, w0f);
    nsf_stage<0><<<NROWS / BM, 256, 0, stream>>>(x, zout, ld, w0f, f0_b0, w1f);
    nsf_stage<1><<<NROWS / BM, 256, 0, stream>>>(x, zout, ld, w0f + 65536, f1_b0,
                                                 w1f + (size_t)W1ELEMS * 8);
}

// Round 8
// 514.619 us; speedup vs baseline: 2.6234x; 1.1754x over previous
//
#include <hip/hip_runtime.h>
#include <math.h>

// NSF_CL coupling flow via bf16 MFMA. N=32768, dim=256 (half=128), hid=512, K=5.
// Round 8 = round 7 structure (transpose-free swapped-operand GEMM2, slim state)
// with spill fix: #pragma unroll 2 on c2 K-loops (bounds compiler load-hoisting
// window), bias k-tile extracted from the loop (no ternary -> no forced full
// unroll), #pragma unroll 1 on the db loop (no cross-d-block interleave).

#define NROWS 32768
#define DIMX  256
#define HALF  128
#define HID   512
#define BM    32

typedef __attribute__((ext_vector_type(8))) short short8;   // 8 bf16 = 4 VGPR
typedef __attribute__((ext_vector_type(4))) float f32x4;

__device__ __forceinline__ unsigned short f2bf(float x) {   // RNE f32->bf16 bits
    unsigned int u = __float_as_uint(x);
    u += 0x7fffu + ((u >> 16) & 1u);
    return (unsigned short)(u >> 16);
}

__device__ __forceinline__ float frcp(float x) { return __builtin_amdgcn_rcpf(x); }

__device__ __forceinline__ float spf(float x) {             // fast softplus
    return fmaxf(x, 0.f) + __logf(1.f + __expf(-fabsf(x)));
}

// cs[p] = cumsum_{0..p} of (1e-3 + 0.995*softmax(6*softmax(P))), p=0..3 (cs[4]==1)
__device__ __forceinline__ void dsm5_cs(const float* P, float* cs) {
    float e[5];
    float m = fmaxf(fmaxf(fmaxf(P[0], P[1]), fmaxf(P[2], P[3])), P[4]);
    float s = 0.f;
    #pragma unroll
    for (int p = 0; p < 5; ++p) { e[p] = __expf(P[p] - m); s += e[p]; }
    float r = 6.f * frcp(s);
    float s2 = 0.f;
    #pragma unroll
    for (int p = 0; p < 5; ++p) { e[p] = __expf(e[p] * r); s2 += e[p]; }
    float r2 = 0.995f * frcp(s2);
    float run = 0.f;
    #pragma unroll
    for (int p = 0; p < 4; ++p) { run += e[p]; cs[p] = (float)(p + 1) * 1.0e-3f + r2 * run; }
}

// ---------- prep ----------
// w1f[stage][frag=(dblk*17+c2)*14+p][lane 64] = ushort8:
//   c2<16 : e -> w1[k=32*c2+8*(l>>4)+e][(dblk*16+(l&15))*14+p]
//   c2==16: e==0 && (l>>4)==0 -> b1[(dblk*16+(l&15))*14+p], else 0   (bias k-tile)
// w0f[stage][ct 32][c 4][lane 64] = ushort8: e -> w0[k=32*c+8*(l>>4)+e][ct*16+(l&15)]
#define W1FRAGS 1904                 // 8*17*14
#define W1ELEMS (W1FRAGS * 64)       // per-stage short8 count = 121856
__global__ void prep(const float* __restrict__ w1a, const float* __restrict__ w1b,
                     const float* __restrict__ w0a, const float* __restrict__ w0b,
                     const float* __restrict__ b1a, const float* __restrict__ b1b,
                     short* __restrict__ w1f, short* __restrict__ w0f) {
    int idx = blockIdx.x * 256 + threadIdx.x;
    if (idx < 2 * W1ELEMS) {
        int s = idx / W1ELEMS;
        int rem = idx - s * W1ELEMS;
        int frag = rem >> 6, l = rem & 63;
        int p = frag % 14;
        int t = frag / 14;
        int c2 = t % 17;
        int dblk = t / 17;
        const float* w1s = s ? w1b : w1a;
        const float* b1s = s ? b1b : b1a;
        int col = (dblk * 16 + (l & 15)) * 14 + p;
        int g = l >> 4;
        short8 o;
        #pragma unroll
        for (int e = 0; e < 8; ++e) {
            float v;
            if (c2 < 16) {
                int k = 32 * c2 + 8 * g + e;
                v = w1s[(size_t)k * 1792 + col];
            } else {
                v = (g == 0 && e == 0) ? b1s[col] : 0.f;
            }
            o[e] = (short)f2bf(v);
        }
        *reinterpret_cast<short8*>(w1f + ((size_t)s * W1ELEMS + rem) * 8) = o;
    } else if (idx < 2 * W1ELEMS + 16384) {
        int r = idx - 2 * W1ELEMS;
        int s = r >> 13, rem = r & 8191;
        int l = rem & 63;
        const float* src = s ? w0b : w0a;
        int p = l & 15, g = l >> 4;
        int ct = rem >> 8, c = (rem >> 6) & 3;
        short8 o;
        #pragma unroll
        for (int e = 0; e < 8; ++e) {
            int k = 32 * c + 8 * g + e;
            o[e] = (short)f2bf(src[k * 512 + ct * 16 + p]);
        }
        *reinterpret_cast<short8*>(w0f + s * 65536 + rem * 8) = o;
    }
}

// ---------- fused stage kernel: 4 waves, 32 rows/block ----------
template <int STAGE>
__global__ __launch_bounds__(256, 3)
void nsf_stage(const float* __restrict__ xin, float* __restrict__ zout,
               float* __restrict__ ld_out,
               const short* __restrict__ w0f, const float* __restrict__ b0,
               const short* __restrict__ w1f) {
    __shared__ __align__(16) short hA2[16384];   // 32 KB: [rt 2][c2 16][lane 64][e 8] bf16
    __shared__ __align__(16) float aux[2048];    // 8 KB: A1 alias (phase 0/1), ld reduce (end)
    short* A1 = reinterpret_cast<short*>(aux);   // 8 frags x 64 lanes x 8 bf16 = 8 KB

    const int tid = threadIdx.x;
    const int lane = tid & 63;
    const int w = tid >> 6;
    const int n0 = blockIdx.x * BM;

    const float* cond = STAGE ? zout : xin;
    const int coff = STAGE ? HALF : 0;
    const int aoff = STAGE ? 0 : HALF;
    const int yoff = STAGE ? 0 : HALF;

    // ---- phase 0: cond tile [32][128] -> bf16 A1 fragments
    #pragma unroll
    for (int t = 0; t < 2; ++t) {
        int idx = t * 256 + tid;             // 8 frags x 64 lanes
        int fr = idx >> 6, l = idx & 63;
        int rt = fr >> 2, c = fr & 3;
        int row = rt * 16 + (l & 15);
        int kb = 32 * c + 8 * (l >> 4);
        const float* sp = cond + (size_t)(n0 + row) * DIMX + coff + kb;
        short8 o;
        #pragma unroll
        for (int e = 0; e < 8; ++e) o[e] = (short)f2bf(sp[e]);
        *reinterpret_cast<short8*>(A1 + idx * 8) = o;
    }
    __syncthreads();

    // ---- phase 1: h = tanh(cond @ w0 + b0) -> bf16 frag order in hA2
    for (int rt = 0; rt < 2; ++rt) {
        short8 a1[4];
        #pragma unroll
        for (int c = 0; c < 4; ++c)
            a1[c] = *reinterpret_cast<const short8*>(A1 + ((rt * 4 + c) * 64 + lane) * 8);
        #pragma unroll
        for (int j = 0; j < 8; ++j) {
            int ct = w * 8 + j;
            f32x4 acc = {0.f, 0.f, 0.f, 0.f};
            #pragma unroll
            for (int c = 0; c < 4; ++c) {
                short8 b = *reinterpret_cast<const short8*>(w0f + ((ct * 4 + c) * 64 + lane) * 8);
                acc = __builtin_amdgcn_mfma_f32_16x16x32_bf16(a1[c], b, acc, 0, 0, 0);
            }
            float bv = b0[ct * 16 + (lane & 15)];
            int q = (2 * ct + ((lane & 15) >> 3)) & 3;
            int c2 = ct >> 1;
            #pragma unroll
            for (int r = 0; r < 4; ++r) {
                float av = acc[r] + bv;
                float e2 = __expf(2.f * av);
                float hvf = 1.f - 2.f * frcp(e2 + 1.f);
                int i = (lane >> 4) * 4 + r;
                hA2[((rt * 16 + c2) * 64 + (i + 16 * q)) * 8 + (lane & 7)] = (short)f2bf(hvf);
            }
        }
    }
    __syncthreads();

    // ---- phase 2: per d-block (16 d), swapped-operand GEMM2 in 3 p-groups.
    // Persistent per tuple (q in 2, r in 4): xa, th, rw (after W), in_ch, in_h
    // (after H); 3-bit bucket idx packed in one uint. D-group finishes in place.
    float ldacc[2] = {0.f, 0.f};
    short8 vone = {0, 0, 0, 0, 0, 0, 0, 0};     // virtual bias k-tile B-frag
    if (lane < 16) vone[0] = (short)0x3F80;      // bf16 1.0

    #pragma unroll 1
    for (int db = 0; db < 2; ++db) {
        const int dblk = w * 2 + db;
        const short* wbase = w1f + (size_t)dblk * 17 * 14 * 512;
        const short* bbase = wbase + (size_t)16 * 14 * 512;   // bias k-tile frags
        float xa[2][4], th[2][4], rw[2][4], inch[2][4], inh[2][4];
        unsigned idxp = 0;

        #pragma unroll
        for (int q = 0; q < 2; ++q)
            #pragma unroll
            for (int r = 0; r < 4; ++r) {
                int n = n0 + q * 16 + (lane & 15);
                int d = dblk * 16 + (lane >> 4) * 4 + r;
                xa[q][r] = xin[(size_t)n * DIMX + aoff + d];
            }

        // --- group W: p = 0..4 -> th, rw, idx
        {
            f32x4 acc[2][5];
            #pragma unroll
            for (int q = 0; q < 2; ++q)
                #pragma unroll
                for (int p = 0; p < 5; ++p) acc[q][p] = (f32x4){0.f, 0.f, 0.f, 0.f};
            #pragma unroll 2
            for (int c2 = 0; c2 < 16; ++c2) {
                short8 hb0 = *reinterpret_cast<const short8*>(hA2 + (c2 * 64 + lane) * 8);
                short8 hb1 = *reinterpret_cast<const short8*>(hA2 + ((16 + c2) * 64 + lane) * 8);
                const short* fb = wbase + (size_t)c2 * 14 * 512 + lane * 8;
                #pragma unroll
                for (int p = 0; p < 5; ++p) {
                    short8 af = *reinterpret_cast<const short8*>(fb + p * 512);
                    acc[0][p] = __builtin_amdgcn_mfma_f32_16x16x32_bf16(af, hb0, acc[0][p], 0, 0, 0);
                    acc[1][p] = __builtin_amdgcn_mfma_f32_16x16x32_bf16(af, hb1, acc[1][p], 0, 0, 0);
                }
            }
            {   // bias k-tile (c2 == 16)
                #pragma unroll
                for (int p = 0; p < 5; ++p) {
                    short8 af = *reinterpret_cast<const short8*>(bbase + p * 512 + lane * 8);
                    acc[0][p] = __builtin_amdgcn_mfma_f32_16x16x32_bf16(af, vone, acc[0][p], 0, 0, 0);
                    acc[1][p] = __builtin_amdgcn_mfma_f32_16x16x32_bf16(af, vone, acc[1][p], 0, 0, 0);
                }
            }
            #pragma unroll
            for (int q = 0; q < 2; ++q)
                #pragma unroll
                for (int r = 0; r < 4; ++r) {
                    float P[5] = {acc[q][0][r], acc[q][1][r], acc[q][2][r], acc[q][3][r], acc[q][4][r]};
                    float cs[4];
                    dsm5_cs(P, cs);
                    float xc = fminf(fmaxf(xa[q][r], -3.f), 3.f);
                    float in_cw = -3.f, in_w = 6.f * cs[0];
                    int idx = 0;
                    #pragma unroll
                    for (int p = 1; p < 5; ++p) {
                        float cwp = 6.f * cs[p - 1] - 3.f;
                        float cwp1 = (p == 4) ? 3.f : (6.f * cs[p] - 3.f);
                        bool take = (xc >= cwp);
                        in_cw = take ? cwp : in_cw;
                        in_w  = take ? (cwp1 - cwp) : in_w;
                        idx   = take ? p : idx;
                    }
                    float rwv = frcp(in_w);
                    rw[q][r] = rwv;
                    th[q][r] = (xc - in_cw) * rwv;
                    idxp |= (unsigned)idx << (3 * (q * 4 + r));
                }
        }
        // --- group H: p = 5..9 -> in_ch, in_h
        {
            f32x4 acc[2][5];
            #pragma unroll
            for (int q = 0; q < 2; ++q)
                #pragma unroll
                for (int p = 0; p < 5; ++p) acc[q][p] = (f32x4){0.f, 0.f, 0.f, 0.f};
            #pragma unroll 2
            for (int c2 = 0; c2 < 16; ++c2) {
                short8 hb0 = *reinterpret_cast<const short8*>(hA2 + (c2 * 64 + lane) * 8);
                short8 hb1 = *reinterpret_cast<const short8*>(hA2 + ((16 + c2) * 64 + lane) * 8);
                const short* fb = wbase + (size_t)c2 * 14 * 512 + lane * 8;
                #pragma unroll
                for (int p = 0; p < 5; ++p) {
                    short8 af = *reinterpret_cast<const short8*>(fb + (5 + p) * 512);
                    acc[0][p] = __builtin_amdgcn_mfma_f32_16x16x32_bf16(af, hb0, acc[0][p], 0, 0, 0);
                    acc[1][p] = __builtin_amdgcn_mfma_f32_16x16x32_bf16(af, hb1, acc[1][p], 0, 0, 0);
                }
            }
            {   // bias k-tile (c2 == 16)
                #pragma unroll
                for (int p = 0; p < 5; ++p) {
                    short8 af = *reinterpret_cast<const short8*>(bbase + (5 + p) * 512 + lane * 8);
                    acc[0][p] = __builtin_amdgcn_mfma_f32_16x16x32_bf16(af, vone, acc[0][p], 0, 0, 0);
                    acc[1][p] = __builtin_amdgcn_mfma_f32_16x16x32_bf16(af, vone, acc[1][p], 0, 0, 0);
                }
            }
            #pragma unroll
            for (int q = 0; q < 2; ++q)
                #pragma unroll
                for (int r = 0; r < 4; ++r) {
                    float P[5] = {acc[q][0][r], acc[q][1][r], acc[q][2][r], acc[q][3][r], acc[q][4][r]};
                    float cs[4];
                    dsm5_cs(P, cs);
                    int idx = (int)((idxp >> (3 * (q * 4 + r))) & 7u);
                    float lo = -3.f, hi = 6.f * cs[0] - 3.f;
                    #pragma unroll
                    for (int p = 1; p < 5; ++p) {
                        float clo = 6.f * cs[p - 1] - 3.f;
                        float chi = (p == 4) ? 3.f : (6.f * cs[p] - 3.f);
                        bool t = (idx >= p);
                        lo = t ? clo : lo;
                        hi = t ? chi : hi;
                    }
                    inch[q][r] = lo;
                    inh[q][r]  = hi - lo;
                }
        }
        // --- group D: p = 10..13 -> dk, dk1; finish spline
        {
            f32x4 acc[2][4];
            #pragma unroll
            for (int q = 0; q < 2; ++q)
                #pragma unroll
                for (int p = 0; p < 4; ++p) acc[q][p] = (f32x4){0.f, 0.f, 0.f, 0.f};
            #pragma unroll 2
            for (int c2 = 0; c2 < 16; ++c2) {
                short8 hb0 = *reinterpret_cast<const short8*>(hA2 + (c2 * 64 + lane) * 8);
                short8 hb1 = *reinterpret_cast<const short8*>(hA2 + ((16 + c2) * 64 + lane) * 8);
                const short* fb = wbase + (size_t)c2 * 14 * 512 + lane * 8;
                #pragma unroll
                for (int p = 0; p < 4; ++p) {
                    short8 af = *reinterpret_cast<const short8*>(fb + (10 + p) * 512);
                    acc[0][p] = __builtin_amdgcn_mfma_f32_16x16x32_bf16(af, hb0, acc[0][p], 0, 0, 0);
                    acc[1][p] = __builtin_amdgcn_mfma_f32_16x16x32_bf16(af, hb1, acc[1][p], 0, 0, 0);
                }
            }
            {   // bias k-tile (c2 == 16)
                #pragma unroll
                for (int p = 0; p < 4; ++p) {
                    short8 af = *reinterpret_cast<const short8*>(bbase + (10 + p) * 512 + lane * 8);
                    acc[0][p] = __builtin_amdgcn_mfma_f32_16x16x32_bf16(af, vone, acc[0][p], 0, 0, 0);
                    acc[1][p] = __builtin_amdgcn_mfma_f32_16x16x32_bf16(af, vone, acc[1][p], 0, 0, 0);
                }
            }
            #pragma unroll
            for (int q = 0; q < 2; ++q)
                #pragma unroll
                for (int r = 0; r < 4; ++r) {
                    float dvi[4];
                    #pragma unroll
                    for (int p = 0; p < 4; ++p) dvi[p] = 1.0e-3f + spf(spf(acc[q][p][r]));
                    int idx = (int)((idxp >> (3 * (q * 4 + r))) & 7u);
                    float dk = 1.f, dk1 = dvi[0];
                    #pragma unroll
                    for (int p = 1; p < 5; ++p) {
                        bool t = (idx >= p);
                        dk = t ? dvi[p - 1] : dk;
                    }
                    #pragma unroll
                    for (int p = 1; p < 4; ++p) {
                        bool t = (idx >= p);
                        dk1 = t ? dvi[p] : dk1;
                    }
                    dk1 = (idx >= 4) ? 1.f : dk1;

                    float xav = xa[q][r], thv = th[q][r], rwv = rw[q][r];
                    float hin = inh[q][r];
                    float om = 1.f - thv;
                    float t1m = thv * om;
                    float delta = hin * rwv;
                    float num = hin * (delta * thv * thv + dk * t1m);
                    float den = delta + (dk + dk1 - 2.f * delta) * t1m;
                    float y = inch[q][r] + num * frcp(den);
                    float dnum = delta * delta * (dk1 * thv * thv + 2.f * delta * t1m + dk * om * om);
                    float ld = __logf(dnum) - 2.f * __logf(den);
                    bool inside = (xav >= -3.f) && (xav <= 3.f);
                    y  = inside ? y : xav;
                    ld = inside ? ld : 0.f;

                    int n = n0 + q * 16 + (lane & 15);
                    int d = dblk * 16 + (lane >> 4) * 4 + r;
                    zout[(size_t)n * DIMX + yoff + d] = y;
                    ldacc[q] += ld;
                }
        }
    }

    // ---- log-det reduce: within wave (d-groups), then across waves via aux
    float s0 = ldacc[0], s1 = ldacc[1];
    s0 += __shfl_xor(s0, 16, 64); s0 += __shfl_xor(s0, 32, 64);
    s1 += __shfl_xor(s1, 16, 64); s1 += __shfl_xor(s1, 32, 64);
    __syncthreads();                             // A1 region long done; order before reuse
    if (lane < 16) {
        aux[w * 32 + lane] = s0;
        aux[w * 32 + 16 + lane] = s1;
    }
    __syncthreads();
    if (tid < BM) {
        float s = aux[tid] + aux[32 + tid] + aux[64 + tid] + aux[96 + tid];
        if (STAGE == 0) ld_out[n0 + tid] = s;
        else            ld_out[n0 + tid] += s;
    }
}

// ---------- launch ----------
extern "C" void kernel_launch(void* const* d_in, const int* in_sizes, int n_in,
                              void* d_out, int out_size, void* d_ws, size_t ws_size,
                              hipStream_t stream) {
    const float* x     = (const float*)d_in[0];
    const float* f0_w0 = (const float*)d_in[1];
    const float* f0_b0 = (const float*)d_in[2];
    const float* f0_w1 = (const float*)d_in[3];
    const float* f0_b1 = (const float*)d_in[4];
    const float* f1_w0 = (const float*)d_in[5];
    const float* f1_b0 = (const float*)d_in[6];
    const float* f1_w1 = (const float*)d_in[7];
    const float* f1_b1 = (const float*)d_in[8];

    float* zout = (float*)d_out;
    float* ld   = zout + (size_t)NROWS * DIMX;

    short* w1f = (short*)d_ws;                                   // 2 x 1.86 MB
    short* w0f = (short*)((char*)d_ws + (size_t)2 * W1ELEMS * 16); // 2 x 128 KB

    prep<<<1016, 256, 0, stream>>>(f0_w1, f1_w1, f0_w0, f1_w0, f0_b1, f1_b1, w1f, w0f);
    nsf_stage<0><<<NROWS / BM, 256, 0, stream>>>(x, zout, ld, w0f, f0_b0, w1f);
    nsf_stage<1><<<NROWS / BM, 256, 0, stream>>>(x, zout, ld, w0f + 65536, f1_b0,
                                                 w1f + (size_t)W1ELEMS * 8);
}

// Round 10
// 432.450 us; speedup vs baseline: 3.1219x; 1.1900x over previous
//
#include <hip/hip_runtime.h>
#include <math.h>

// NSF_CL coupling flow via bf16 MFMA. N=32768, dim=256 (half=128), hid=512, K=5.
// Round 10 = round 9 resubmitted verbatim (r9 bench was an acquisition timeout):
//   launch_bounds(256,2) (256-reg budget; compiler's arch/AGPR split has slack)
//   #pragma unroll 4 on c2 K-loops (more outstanding L2 loads for latency hiding)
// Structure: transpose-free swapped-operand GEMM2 (A=w1 d-rows, B=h batch cols),
// bias as virtual k-tile, slim per-thread spline state (idx decided after W).

#define NROWS 32768
#define DIMX  256
#define HALF  128
#define HID   512
#define BM    32

typedef __attribute__((ext_vector_type(8))) short short8;   // 8 bf16 = 4 VGPR
typedef __attribute__((ext_vector_type(4))) float f32x4;

__device__ __forceinline__ unsigned short f2bf(float x) {   // RNE f32->bf16 bits
    unsigned int u = __float_as_uint(x);
    u += 0x7fffu + ((u >> 16) & 1u);
    return (unsigned short)(u >> 16);
}

__device__ __forceinline__ float frcp(float x) { return __builtin_amdgcn_rcpf(x); }

__device__ __forceinline__ float spf(float x) {             // fast softplus
    return fmaxf(x, 0.f) + __logf(1.f + __expf(-fabsf(x)));
}

// cs[p] = cumsum_{0..p} of (1e-3 + 0.995*softmax(6*softmax(P))), p=0..3 (cs[4]==1)
__device__ __forceinline__ void dsm5_cs(const float* P, float* cs) {
    float e[5];
    float m = fmaxf(fmaxf(fmaxf(P[0], P[1]), fmaxf(P[2], P[3])), P[4]);
    float s = 0.f;
    #pragma unroll
    for (int p = 0; p < 5; ++p) { e[p] = __expf(P[p] - m); s += e[p]; }
    float r = 6.f * frcp(s);
    float s2 = 0.f;
    #pragma unroll
    for (int p = 0; p < 5; ++p) { e[p] = __expf(e[p] * r); s2 += e[p]; }
    float r2 = 0.995f * frcp(s2);
    float run = 0.f;
    #pragma unroll
    for (int p = 0; p < 4; ++p) { run += e[p]; cs[p] = (float)(p + 1) * 1.0e-3f + r2 * run; }
}

// ---------- prep ----------
// w1f[stage][frag=(dblk*17+c2)*14+p][lane 64] = ushort8:
//   c2<16 : e -> w1[k=32*c2+8*(l>>4)+e][(dblk*16+(l&15))*14+p]
//   c2==16: e==0 && (l>>4)==0 -> b1[(dblk*16+(l&15))*14+p], else 0   (bias k-tile)
// w0f[stage][ct 32][c 4][lane 64] = ushort8: e -> w0[k=32*c+8*(l>>4)+e][ct*16+(l&15)]
#define W1FRAGS 1904                 // 8*17*14
#define W1ELEMS (W1FRAGS * 64)       // per-stage short8 count = 121856
__global__ void prep(const float* __restrict__ w1a, const float* __restrict__ w1b,
                     const float* __restrict__ w0a, const float* __restrict__ w0b,
                     const float* __restrict__ b1a, const float* __restrict__ b1b,
                     short* __restrict__ w1f, short* __restrict__ w0f) {
    int idx = blockIdx.x * 256 + threadIdx.x;
    if (idx < 2 * W1ELEMS) {
        int s = idx / W1ELEMS;
        int rem = idx - s * W1ELEMS;
        int frag = rem >> 6, l = rem & 63;
        int p = frag % 14;
        int t = frag / 14;
        int c2 = t % 17;
        int dblk = t / 17;
        const float* w1s = s ? w1b : w1a;
        const float* b1s = s ? b1b : b1a;
        int col = (dblk * 16 + (l & 15)) * 14 + p;
        int g = l >> 4;
        short8 o;
        #pragma unroll
        for (int e = 0; e < 8; ++e) {
            float v;
            if (c2 < 16) {
                int k = 32 * c2 + 8 * g + e;
                v = w1s[(size_t)k * 1792 + col];
            } else {
                v = (g == 0 && e == 0) ? b1s[col] : 0.f;
            }
            o[e] = (short)f2bf(v);
        }
        *reinterpret_cast<short8*>(w1f + ((size_t)s * W1ELEMS + rem) * 8) = o;
    } else if (idx < 2 * W1ELEMS + 16384) {
        int r = idx - 2 * W1ELEMS;
        int s = r >> 13, rem = r & 8191;
        int l = rem & 63;
        const float* src = s ? w0b : w0a;
        int p = l & 15, g = l >> 4;
        int ct = rem >> 8, c = (rem >> 6) & 3;
        short8 o;
        #pragma unroll
        for (int e = 0; e < 8; ++e) {
            int k = 32 * c + 8 * g + e;
            o[e] = (short)f2bf(src[k * 512 + ct * 16 + p]);
        }
        *reinterpret_cast<short8*>(w0f + s * 65536 + rem * 8) = o;
    }
}

// ---------- fused stage kernel: 4 waves, 32 rows/block ----------
template <int STAGE>
__global__ __launch_bounds__(256, 2)
void nsf_stage(const float* __restrict__ xin, float* __restrict__ zout,
               float* __restrict__ ld_out,
               const short* __restrict__ w0f, const float* __restrict__ b0,
               const short* __restrict__ w1f) {
    __shared__ __align__(16) short hA2[16384];   // 32 KB: [rt 2][c2 16][lane 64][e 8] bf16
    __shared__ __align__(16) float aux[2048];    // 8 KB: A1 alias (phase 0/1), ld reduce (end)
    short* A1 = reinterpret_cast<short*>(aux);   // 8 frags x 64 lanes x 8 bf16 = 8 KB

    const int tid = threadIdx.x;
    const int lane = tid & 63;
    const int w = tid >> 6;
    const int n0 = blockIdx.x * BM;

    const float* cond = STAGE ? zout : xin;
    const int coff = STAGE ? HALF : 0;
    const int aoff = STAGE ? 0 : HALF;
    const int yoff = STAGE ? 0 : HALF;

    // ---- phase 0: cond tile [32][128] -> bf16 A1 fragments
    #pragma unroll
    for (int t = 0; t < 2; ++t) {
        int idx = t * 256 + tid;             // 8 frags x 64 lanes
        int fr = idx >> 6, l = idx & 63;
        int rt = fr >> 2, c = fr & 3;
        int row = rt * 16 + (l & 15);
        int kb = 32 * c + 8 * (l >> 4);
        const float* sp = cond + (size_t)(n0 + row) * DIMX + coff + kb;
        short8 o;
        #pragma unroll
        for (int e = 0; e < 8; ++e) o[e] = (short)f2bf(sp[e]);
        *reinterpret_cast<short8*>(A1 + idx * 8) = o;
    }
    __syncthreads();

    // ---- phase 1: h = tanh(cond @ w0 + b0) -> bf16 frag order in hA2
    for (int rt = 0; rt < 2; ++rt) {
        short8 a1[4];
        #pragma unroll
        for (int c = 0; c < 4; ++c)
            a1[c] = *reinterpret_cast<const short8*>(A1 + ((rt * 4 + c) * 64 + lane) * 8);
        #pragma unroll
        for (int j = 0; j < 8; ++j) {
            int ct = w * 8 + j;
            f32x4 acc = {0.f, 0.f, 0.f, 0.f};
            #pragma unroll
            for (int c = 0; c < 4; ++c) {
                short8 b = *reinterpret_cast<const short8*>(w0f + ((ct * 4 + c) * 64 + lane) * 8);
                acc = __builtin_amdgcn_mfma_f32_16x16x32_bf16(a1[c], b, acc, 0, 0, 0);
            }
            float bv = b0[ct * 16 + (lane & 15)];
            int q = (2 * ct + ((lane & 15) >> 3)) & 3;
            int c2 = ct >> 1;
            #pragma unroll
            for (int r = 0; r < 4; ++r) {
                float av = acc[r] + bv;
                float e2 = __expf(2.f * av);
                float hvf = 1.f - 2.f * frcp(e2 + 1.f);
                int i = (lane >> 4) * 4 + r;
                hA2[((rt * 16 + c2) * 64 + (i + 16 * q)) * 8 + (lane & 7)] = (short)f2bf(hvf);
            }
        }
    }
    __syncthreads();

    // ---- phase 2: per d-block (16 d), swapped-operand GEMM2 in 3 p-groups.
    // Persistent per tuple (q in 2, r in 4): xa, th, rw (after W), in_ch, in_h
    // (after H); 3-bit bucket idx packed in one uint. D-group finishes in place.
    float ldacc[2] = {0.f, 0.f};
    short8 vone = {0, 0, 0, 0, 0, 0, 0, 0};     // virtual bias k-tile B-frag
    if (lane < 16) vone[0] = (short)0x3F80;      // bf16 1.0

    #pragma unroll 1
    for (int db = 0; db < 2; ++db) {
        const int dblk = w * 2 + db;
        const short* wbase = w1f + (size_t)dblk * 17 * 14 * 512;
        const short* bbase = wbase + (size_t)16 * 14 * 512;   // bias k-tile frags
        float xa[2][4], th[2][4], rw[2][4], inch[2][4], inh[2][4];
        unsigned idxp = 0;

        #pragma unroll
        for (int q = 0; q < 2; ++q)
            #pragma unroll
            for (int r = 0; r < 4; ++r) {
                int n = n0 + q * 16 + (lane & 15);
                int d = dblk * 16 + (lane >> 4) * 4 + r;
                xa[q][r] = xin[(size_t)n * DIMX + aoff + d];
            }

        // --- group W: p = 0..4 -> th, rw, idx
        {
            f32x4 acc[2][5];
            #pragma unroll
            for (int q = 0; q < 2; ++q)
                #pragma unroll
                for (int p = 0; p < 5; ++p) acc[q][p] = (f32x4){0.f, 0.f, 0.f, 0.f};
            #pragma unroll 4
            for (int c2 = 0; c2 < 16; ++c2) {
                short8 hb0 = *reinterpret_cast<const short8*>(hA2 + (c2 * 64 + lane) * 8);
                short8 hb1 = *reinterpret_cast<const short8*>(hA2 + ((16 + c2) * 64 + lane) * 8);
                const short* fb = wbase + (size_t)c2 * 14 * 512 + lane * 8;
                #pragma unroll
                for (int p = 0; p < 5; ++p) {
                    short8 af = *reinterpret_cast<const short8*>(fb + p * 512);
                    acc[0][p] = __builtin_amdgcn_mfma_f32_16x16x32_bf16(af, hb0, acc[0][p], 0, 0, 0);
                    acc[1][p] = __builtin_amdgcn_mfma_f32_16x16x32_bf16(af, hb1, acc[1][p], 0, 0, 0);
                }
            }
            {   // bias k-tile (c2 == 16)
                #pragma unroll
                for (int p = 0; p < 5; ++p) {
                    short8 af = *reinterpret_cast<const short8*>(bbase + p * 512 + lane * 8);
                    acc[0][p] = __builtin_amdgcn_mfma_f32_16x16x32_bf16(af, vone, acc[0][p], 0, 0, 0);
                    acc[1][p] = __builtin_amdgcn_mfma_f32_16x16x32_bf16(af, vone, acc[1][p], 0, 0, 0);
                }
            }
            #pragma unroll
            for (int q = 0; q < 2; ++q)
                #pragma unroll
                for (int r = 0; r < 4; ++r) {
                    float P[5] = {acc[q][0][r], acc[q][1][r], acc[q][2][r], acc[q][3][r], acc[q][4][r]};
                    float cs[4];
                    dsm5_cs(P, cs);
                    float xc = fminf(fmaxf(xa[q][r], -3.f), 3.f);
                    float in_cw = -3.f, in_w = 6.f * cs[0];
                    int idx = 0;
                    #pragma unroll
                    for (int p = 1; p < 5; ++p) {
                        float cwp = 6.f * cs[p - 1] - 3.f;
                        float cwp1 = (p == 4) ? 3.f : (6.f * cs[p] - 3.f);
                        bool take = (xc >= cwp);
                        in_cw = take ? cwp : in_cw;
                        in_w  = take ? (cwp1 - cwp) : in_w;
                        idx   = take ? p : idx;
                    }
                    float rwv = frcp(in_w);
                    rw[q][r] = rwv;
                    th[q][r] = (xc - in_cw) * rwv;
                    idxp |= (unsigned)idx << (3 * (q * 4 + r));
                }
        }
        // --- group H: p = 5..9 -> in_ch, in_h
        {
            f32x4 acc[2][5];
            #pragma unroll
            for (int q = 0; q < 2; ++q)
                #pragma unroll
                for (int p = 0; p < 5; ++p) acc[q][p] = (f32x4){0.f, 0.f, 0.f, 0.f};
            #pragma unroll 4
            for (int c2 = 0; c2 < 16; ++c2) {
                short8 hb0 = *reinterpret_cast<const short8*>(hA2 + (c2 * 64 + lane) * 8);
                short8 hb1 = *reinterpret_cast<const short8*>(hA2 + ((16 + c2) * 64 + lane) * 8);
                const short* fb = wbase + (size_t)c2 * 14 * 512 + lane * 8;
                #pragma unroll
                for (int p = 0; p < 5; ++p) {
                    short8 af = *reinterpret_cast<const short8*>(fb + (5 + p) * 512);
                    acc[0][p] = __builtin_amdgcn_mfma_f32_16x16x32_bf16(af, hb0, acc[0][p], 0, 0, 0);
                    acc[1][p] = __builtin_amdgcn_mfma_f32_16x16x32_bf16(af, hb1, acc[1][p], 0, 0, 0);
                }
            }
            {   // bias k-tile (c2 == 16)
                #pragma unroll
                for (int p = 0; p < 5; ++p) {
                    short8 af = *reinterpret_cast<const short8*>(bbase + (5 + p) * 512 + lane * 8);
                    acc[0][p] = __builtin_amdgcn_mfma_f32_16x16x32_bf16(af, vone, acc[0][p], 0, 0, 0);
                    acc[1][p] = __builtin_amdgcn_mfma_f32_16x16x32_bf16(af, vone, acc[1][p], 0, 0, 0);
                }
            }
            #pragma unroll
            for (int q = 0; q < 2; ++q)
                #pragma unroll
                for (int r = 0; r < 4; ++r) {
                    float P[5] = {acc[q][0][r], acc[q][1][r], acc[q][2][r], acc[q][3][r], acc[q][4][r]};
                    float cs[4];
                    dsm5_cs(P, cs);
                    int idx = (int)((idxp >> (3 * (q * 4 + r))) & 7u);
                    float lo = -3.f, hi = 6.f * cs[0] - 3.f;
                    #pragma unroll
                    for (int p = 1; p < 5; ++p) {
                        float clo = 6.f * cs[p - 1] - 3.f;
                        float chi = (p == 4) ? 3.f : (6.f * cs[p] - 3.f);
                        bool t = (idx >= p);
                        lo = t ? clo : lo;
                        hi = t ? chi : hi;
                    }
                    inch[q][r] = lo;
                    inh[q][r]  = hi - lo;
                }
        }
        // --- group D: p = 10..13 -> dk, dk1; finish spline
        {
            f32x4 acc[2][4];
            #pragma unroll
            for (int q = 0; q < 2; ++q)
                #pragma unroll
                for (int p = 0; p < 4; ++p) acc[q][p] = (f32x4){0.f, 0.f, 0.f, 0.f};
            #pragma unroll 4
            for (int c2 = 0; c2 < 16; ++c2) {
                short8 hb0 = *reinterpret_cast<const short8*>(hA2 + (c2 * 64 + lane) * 8);
                short8 hb1 = *reinterpret_cast<const short8*>(hA2 + ((16 + c2) * 64 + lane) * 8);
                const short* fb = wbase + (size_t)c2 * 14 * 512 + lane * 8;
                #pragma unroll
                for (int p = 0; p < 4; ++p) {
                    short8 af = *reinterpret_cast<const short8*>(fb + (10 + p) * 512);
                    acc[0][p] = __builtin_amdgcn_mfma_f32_16x16x32_bf16(af, hb0, acc[0][p], 0, 0, 0);
                    acc[1][p] = __builtin_amdgcn_mfma_f32_16x16x32_bf16(af, hb1, acc[1][p], 0, 0, 0);
                }
            }
            {   // bias k-tile (c2 == 16)
                #pragma unroll
                for (int p = 0; p < 4; ++p) {
                    short8 af = *reinterpret_cast<const short8*>(bbase + (10 + p) * 512 + lane * 8);
                    acc[0][p] = __builtin_amdgcn_mfma_f32_16x16x32_bf16(af, vone, acc[0][p], 0, 0, 0);
                    acc[1][p] = __builtin_amdgcn_mfma_f32_16x16x32_bf16(af, vone, acc[1][p], 0, 0, 0);
                }
            }
            #pragma unroll
            for (int q = 0; q < 2; ++q)
                #pragma unroll
                for (int r = 0; r < 4; ++r) {
                    float dvi[4];
                    #pragma unroll
                    for (int p = 0; p < 4; ++p) dvi[p] = 1.0e-3f + spf(spf(acc[q][p][r]));
                    int idx = (int)((idxp >> (3 * (q * 4 + r))) & 7u);
                    float dk = 1.f, dk1 = dvi[0];
                    #pragma unroll
                    for (int p = 1; p < 5; ++p) {
                        bool t = (idx >= p);
                        dk = t ? dvi[p - 1] : dk;
                    }
                    #pragma unroll
                    for (int p = 1; p < 4; ++p) {
                        bool t = (idx >= p);
                        dk1 = t ? dvi[p] : dk1;
                    }
                    dk1 = (idx >= 4) ? 1.f : dk1;

                    float xav = xa[q][r], thv = th[q][r], rwv = rw[q][r];
                    float hin = inh[q][r];
                    float om = 1.f - thv;
                    float t1m = thv * om;
                    float delta = hin * rwv;
                    float num = hin * (delta * thv * thv + dk * t1m);
                    float den = delta + (dk + dk1 - 2.f * delta) * t1m;
                    float y = inch[q][r] + num * frcp(den);
                    float dnum = delta * delta * (dk1 * thv * thv + 2.f * delta * t1m + dk * om * om);
                    float ld = __logf(dnum) - 2.f * __logf(den);
                    bool inside = (xav >= -3.f) && (xav <= 3.f);
                    y  = inside ? y : xav;
                    ld = inside ? ld : 0.f;

                    int n = n0 + q * 16 + (lane & 15);
                    int d = dblk * 16 + (lane >> 4) * 4 + r;
                    zout[(size_t)n * DIMX + yoff + d] = y;
                    ldacc[q] += ld;
                }
        }
    }

    // ---- log-det reduce: within wave (d-groups), then across waves via aux
    float s0 = ldacc[0], s1 = ldacc[1];
    s0 += __shfl_xor(s0, 16, 64); s0 += __shfl_xor(s0, 32, 64);
    s1 += __shfl_xor(s1, 16, 64); s1 += __shfl_xor(s1, 32, 64);
    __syncthreads();                             // A1 region long done; order before reuse
    if (lane < 16) {
        aux[w * 32 + lane] = s0;
        aux[w * 32 + 16 + lane] = s1;
    }
    __syncthreads();
    if (tid < BM) {
        float s = aux[tid] + aux[32 + tid] + aux[64 + tid] + aux[96 + tid];
        if (STAGE == 0) ld_out[n0 + tid] = s;
        else            ld_out[n0 + tid] += s;
    }
}

// ---------- launch ----------
extern "C" void kernel_launch(void* const* d_in, const int* in_sizes, int n_in,
                              void* d_out, int out_size, void* d_ws, size_t ws_size,
                              hipStream_t stream) {
    const float* x     = (const float*)d_in[0];
    const float* f0_w0 = (const float*)d_in[1];
    const float* f0_b0 = (const float*)d_in[2];
    const float* f0_w1 = (const float*)d_in[3];
    const float* f0_b1 = (const float*)d_in[4];
    const float* f1_w0 = (const float*)d_in[5];
    const float* f1_b0 = (const float*)d_in[6];
    const float* f1_w1 = (const float*)d_in[7];
    const float* f1_b1 = (const float*)d_in[8];

    float* zout = (float*)d_out;
    float* ld   = zout + (size_t)NROWS * DIMX;

    short* w1f = (short*)d_ws;                                   // 2 x 1.86 MB
    short* w0f = (short*)((char*)d_ws + (size_t)2 * W1ELEMS * 16); // 2 x 128 KB

    prep<<<1016, 256, 0, stream>>>(f0_w1, f1_w1, f0_w0, f1_w0, f0_b1, f1_b1, w1f, w0f);
    nsf_stage<0><<<NROWS / BM, 256, 0, stream>>>(x, zout, ld, w0f, f0_b0, w1f);
    nsf_stage<1><<<NROWS / BM, 256, 0, stream>>>(x, zout, ld, w0f + 65536, f1_b0,
                                                 w1f + (size_t)W1ELEMS * 8);
}